// Round 11
// baseline (201.391 us; speedup 1.0000x reference)
//
#include <hip/hip_runtime.h>

#define LLEN 8192
#define CG 16
#define NG 512   // b(16) * GROUPS(32)

typedef float f32x4 __attribute__((ext_vector_type(4)));

__device__ __forceinline__ uint32_t bf16rne(float f) {
    uint32_t u = __float_as_uint(f);
    return (u + 0x7FFFu + ((u >> 16) & 1u)) >> 16;
}
__device__ __forceinline__ uint32_t packbf(float lo, float hi) {
    return bf16rne(lo) | (bf16rne(hi) << 16);
}
__device__ __forceinline__ float unlo(uint32_t p) { return __uint_as_float(p << 16); }
__device__ __forceinline__ float unhi(uint32_t p) { return __uint_as_float(p & 0xFFFF0000u); }

// ---------------- Pass 1: row sums (+ optional bf16 copy) + per-group prep ---------
// One block per group, 1024 thr = 16 waves; wave w sums row w.
// WRITE_XC=1: x read with NT loads (never re-read -> don't claim L3); bf16 copy
// written with regular stores (134 MB -> comfortably L3-resident for pass 2).
template <int WRITE_XC>
__global__ __launch_bounds__(1024) void sumprep_kernel(const float* __restrict__ x,
                                                       const float* __restrict__ w1,
                                                       const float* __restrict__ b1,
                                                       const float* __restrict__ w3,
                                                       const float* __restrict__ b3,
                                                       float* __restrict__ vw,
                                                       uint32_t* __restrict__ xc) {
    int g    = blockIdx.x;              // 0..511
    int wave = threadIdx.x >> 6;        // row within group
    int lane = threadIdx.x & 63;
    __shared__ float S_lds[CG], F_lds[CG], L_lds[CG];

    const int row = g * CG + wave;
    const f32x4* xr = reinterpret_cast<const f32x4*>(x + (size_t)row * LLEN);
    uint32_t* xcr = xc + (size_t)row * (LLEN / 2);
    float s = 0.f;
    #pragma unroll
    for (int k = 0; k < 32; ++k) {
        f32x4 v;
        if (WRITE_XC) v = __builtin_nontemporal_load(xr + k * 64 + lane);
        else          v = xr[k * 64 + lane];
        s += (v.x + v.y) + (v.z + v.w);
        if (WRITE_XC) {
            *reinterpret_cast<uint2*>(xcr + (size_t)(k * 64 + lane) * 2) =
                make_uint2(packbf(v.x, v.y), packbf(v.z, v.w));
        }
    }
    #pragma unroll
    for (int off = 32; off; off >>= 1)
        s += __shfl_down(s, off, 64);
    if (lane == 0) S_lds[wave] = s;
    if (threadIdx.x < CG) {
        size_t rb = (size_t)(g * CG + threadIdx.x) * LLEN;
        F_lds[threadIdx.x] = x[rb];
        L_lds[threadIdx.x] = x[rb + (LLEN - 1)];
    }
    __syncthreads();

    if (wave == 0) {
        int i = lane & 15;
        const float invL = 1.0f / (float)LLEN;
        float s1 = 0.f, s2 = 0.f;
        #pragma unroll
        for (int k = 0; k < CG; ++k) {
            float Sk = S_lds[k], Fk = F_lds[k], Lk = L_lds[k];
            s1 += w1[i * CG + k] * Sk;
            const float* w = &w3[(i * CG + k) * 3];
            s2 += w[0] * (Sk - Lk) + w[1] * Sk + w[2] * (Sk - Fk);
        }
        float m1 = s1 * invL + b1[i];
        float m2 = s2 * invL + b3[i];

        float mx1 = m1, mx2 = m2;
        #pragma unroll
        for (int off = 8; off; off >>= 1) {
            mx1 = fmaxf(mx1, __shfl_xor(mx1, off, 16));
            mx2 = fmaxf(mx2, __shfl_xor(mx2, off, 16));
        }
        float e1 = __expf(m1 - mx1), e2 = __expf(m2 - mx2);
        float d1 = e1, d2 = e2;
        #pragma unroll
        for (int off = 8; off; off >>= 1) {
            d1 += __shfl_xor(d1, off, 16);
            d2 += __shfl_xor(d2, off, 16);
        }
        float a1 = e1 / d1, a2 = e2 / d2;

        float cb = a1 * b3[i] + a2 * b1[i];
        #pragma unroll
        for (int off = 8; off; off >>= 1) cb += __shfl_xor(cb, off, 16);

        float v0 = 0.f, v1v = 0.f, v2 = 0.f;
        #pragma unroll
        for (int k = 0; k < CG; ++k) {
            float a1k = __shfl(a1, k, 16);
            float a2k = __shfl(a2, k, 16);
            const float* w = &w3[(k * CG + i) * 3];
            v0  += a1k * w[0];
            v1v += a1k * w[1] + a2k * w1[k * CG + i];
            v2  += a1k * w[2];
        }
        if (lane < 16) {
            float* outv = &vw[g * 64];
            outv[i]      = v0;
            outv[16 + i] = v1v;
            outv[32 + i] = v2;
            if (lane == 0) outv[48] = cb;
        }
    }
}

// ---------------- Pass 2 (compressed): bf16 copy -> gate -> NT fp32 out ----------
// One wave per (group, 256-col chunk), REVERSE order (freshest xc lines first).
__global__ __launch_bounds__(256) void apply_c_kernel(const uint32_t* __restrict__ xc,
                                                      const float* __restrict__ vw,
                                                      float* __restrict__ out) {
    int wavg = (blockIdx.x * 256 + threadIdx.x) >> 6;   // 0..16383
    int lane = threadIdx.x & 63;
    int g  = NG - 1 - (wavg >> 5);
    int c0 = (31 - (wavg & 31)) * 256;
    const float* vp = &vw[g * 64];

    const float cb = vp[48];
    float w0 = cb, w1a = cb, w2a = cb, w3a = cb;
    uint2 xv[CG];
    #pragma unroll
    for (int i = 0; i < CG; ++i) {
        size_t ru = (size_t)(g * CG + i) * (LLEN / 2);
        uint2 m = *reinterpret_cast<const uint2*>(xc + ru + c0 / 2 + 2 * lane);
        xv[i] = m;
        float a0 = unlo(m.x), a1 = unhi(m.x), a2 = unlo(m.y), a3 = unhi(m.y);
        float fl = __shfl_up(a3, 1, 64);
        float fr = __shfl_down(a0, 1, 64);
        if (lane == 0)  fl = (c0 > 0) ? unhi(xc[ru + c0 / 2 - 1]) : 0.f;
        if (lane == 63) fr = (c0 + 256 < LLEN) ? unlo(xc[ru + (c0 + 256) / 2]) : 0.f;
        const float t0 = vp[i], t1 = vp[16 + i], t2 = vp[32 + i];
        w0  += t0 * fl + t1 * a0 + t2 * a1;
        w1a += t0 * a0 + t1 * a1 + t2 * a2;
        w2a += t0 * a1 + t1 * a2 + t2 * a3;
        w3a += t0 * a2 + t1 * a3 + t2 * fr;
    }
    const float s0 = 1.f / (1.f + __expf(-w0));
    const float s1 = 1.f / (1.f + __expf(-w1a));
    const float s2 = 1.f / (1.f + __expf(-w2a));
    const float s3 = 1.f / (1.f + __expf(-w3a));
    #pragma unroll
    for (int i = 0; i < CG; ++i) {
        size_t rb = (size_t)(g * CG + i) * LLEN + c0 + 4 * lane;
        uint2 m = xv[i];
        f32x4 o4 = { unlo(m.x) * s0, unhi(m.x) * s1, unlo(m.y) * s2, unhi(m.y) * s3 };
        __builtin_nontemporal_store(o4, reinterpret_cast<f32x4*>(out + rb));
    }
}

// ---------------- Pass 2 (fallback, round-4 proven): fp32 x, forward, NT out ------
__global__ __launch_bounds__(256) void apply_f_kernel(const float* __restrict__ x,
                                                      const float* __restrict__ vw,
                                                      float* __restrict__ out) {
    int wavg = (blockIdx.x * 256 + threadIdx.x) >> 6;
    int lane = threadIdx.x & 63;
    int g  = wavg >> 5;
    int c0 = (wavg & 31) * 256;
    const float* vp = &vw[g * 64];

    const float cb = vp[48];
    float w0 = cb, w1a = cb, w2a = cb, w3a = cb;
    float4 xv[CG];
    #pragma unroll
    for (int i = 0; i < CG; ++i) {
        size_t rb = ((size_t)(g * CG + i)) * LLEN + c0;
        float4 v = *reinterpret_cast<const float4*>(x + rb + 4 * lane);
        xv[i] = v;
        float le = 0.f, re = 0.f;
        if (c0 > 0)            le = x[rb - 1];
        if (c0 + 256 < LLEN)   re = x[rb + 256];
        float fl = __shfl_up(v.w, 1, 64);
        if (lane == 0)  fl = le;
        float fr = __shfl_down(v.x, 1, 64);
        if (lane == 63) fr = re;
        const float a0 = vp[i], a1 = vp[16 + i], a2 = vp[32 + i];
        w0  += a0 * fl  + a1 * v.x + a2 * v.y;
        w1a += a0 * v.x + a1 * v.y + a2 * v.z;
        w2a += a0 * v.y + a1 * v.z + a2 * v.w;
        w3a += a0 * v.z + a1 * v.w + a2 * fr;
    }
    const float s0 = 1.f / (1.f + __expf(-w0));
    const float s1 = 1.f / (1.f + __expf(-w1a));
    const float s2 = 1.f / (1.f + __expf(-w2a));
    const float s3 = 1.f / (1.f + __expf(-w3a));
    #pragma unroll
    for (int i = 0; i < CG; ++i) {
        size_t rb = ((size_t)(g * CG + i)) * LLEN + c0 + 4 * lane;
        float4 v = xv[i];
        f32x4 o4 = { v.x * s0, v.y * s1, v.z * s2, v.w * s3 };
        __builtin_nontemporal_store(o4, reinterpret_cast<f32x4*>(out + rb));
    }
}

extern "C" void kernel_launch(void* const* d_in, const int* in_sizes, int n_in,
                              void* d_out, int out_size, void* d_ws, size_t ws_size,
                              hipStream_t stream) {
    const float* x  = (const float*)d_in[0];
    const float* w1 = (const float*)d_in[1];
    const float* b1 = (const float*)d_in[2];
    const float* w3 = (const float*)d_in[3];
    const float* b3 = (const float*)d_in[4];
    float* out = (float*)d_out;

    const size_t VW_BYTES = (size_t)NG * 64 * 4;                 // 131072
    const size_t XC_BYTES = (size_t)NG * CG * LLEN * 2;          // 134217728
    float*    vw = (float*)d_ws;
    uint32_t* xc = (uint32_t*)((char*)d_ws + VW_BYTES);

    if (ws_size >= VW_BYTES + XC_BYTES) {
        sumprep_kernel<1><<<NG, 1024, 0, stream>>>(x, w1, b1, w3, b3, vw, xc);
        apply_c_kernel<<<4096, 256, 0, stream>>>(xc, vw, out);
    } else {
        sumprep_kernel<0><<<NG, 1024, 0, stream>>>(x, w1, b1, w3, b3, vw, xc);
        apply_f_kernel<<<4096, 256, 0, stream>>>(x, vw, out);
    }
}

// Round 12
// 127.736 us; speedup vs baseline: 1.5766x; 1.5766x over previous
//
#include <hip/hip_runtime.h>

#define LLEN 8192
#define CG 16
#define NG 512   // b(16) * GROUPS(32)

typedef float f32x4 __attribute__((ext_vector_type(4)));

// ---------------- Pass 1: row sums + per-group prep, fused. One block per group. ----
// 1024 threads = 16 waves; wave w sums row w. Then wave 0 computes softmax weights
// and the collapsed 3-tap vectors v0,v1,v2 and scalar bias c, writes vw[g*64..].
__global__ __launch_bounds__(1024) void sumprep_kernel(const float* __restrict__ x,
                                                       const float* __restrict__ w1,
                                                       const float* __restrict__ b1,
                                                       const float* __restrict__ w3,
                                                       const float* __restrict__ b3,
                                                       float* __restrict__ vw) {
    int g    = blockIdx.x;              // 0..511
    int wave = threadIdx.x >> 6;        // 0..15  == row within group
    int lane = threadIdx.x & 63;
    __shared__ float S_lds[CG], F_lds[CG], L_lds[CG];

    const float4* xr = reinterpret_cast<const float4*>(x + (size_t)(g * CG + wave) * LLEN);
    float s = 0.f;
    #pragma unroll
    for (int k = 0; k < 32; ++k) {
        float4 v = xr[k * 64 + lane];
        s += (v.x + v.y) + (v.z + v.w);
    }
    #pragma unroll
    for (int off = 32; off; off >>= 1)
        s += __shfl_down(s, off, 64);
    if (lane == 0) S_lds[wave] = s;
    if (threadIdx.x < CG) {
        size_t rb = (size_t)(g * CG + threadIdx.x) * LLEN;
        F_lds[threadIdx.x] = x[rb];
        L_lds[threadIdx.x] = x[rb + (LLEN - 1)];
    }
    __syncthreads();

    if (wave == 0) {
        int i = lane & 15;              // channel index (lanes 16..63 duplicate)
        const float invL = 1.0f / (float)LLEN;
        float s1 = 0.f, s2 = 0.f;
        #pragma unroll
        for (int k = 0; k < CG; ++k) {
            float Sk = S_lds[k], Fk = F_lds[k], Lk = L_lds[k];
            s1 += w1[i * CG + k] * Sk;
            const float* w = &w3[(i * CG + k) * 3];
            s2 += w[0] * (Sk - Lk) + w[1] * Sk + w[2] * (Sk - Fk);
        }
        float m1 = s1 * invL + b1[i];
        float m2 = s2 * invL + b3[i];

        // softmax across the 16-lane group (both heads)
        float mx1 = m1, mx2 = m2;
        #pragma unroll
        for (int off = 8; off; off >>= 1) {
            mx1 = fmaxf(mx1, __shfl_xor(mx1, off, 16));
            mx2 = fmaxf(mx2, __shfl_xor(mx2, off, 16));
        }
        float e1 = __expf(m1 - mx1), e2 = __expf(m2 - mx2);
        float d1 = e1, d2 = e2;
        #pragma unroll
        for (int off = 8; off; off >>= 1) {
            d1 += __shfl_xor(d1, off, 16);
            d2 += __shfl_xor(d2, off, 16);
        }
        float a1 = e1 / d1, a2 = e2 / d2;

        float cb = a1 * b3[i] + a2 * b1[i];
        #pragma unroll
        for (int off = 8; off; off >>= 1) cb += __shfl_xor(cb, off, 16);

        float v0 = 0.f, v1v = 0.f, v2 = 0.f;
        #pragma unroll
        for (int k = 0; k < CG; ++k) {
            float a1k = __shfl(a1, k, 16);
            float a2k = __shfl(a2, k, 16);
            const float* w = &w3[(k * CG + i) * 3];
            v0  += a1k * w[0];
            v1v += a1k * w[1] + a2k * w1[k * CG + i];
            v2  += a1k * w[2];
        }
        if (lane < 16) {
            float* outv = &vw[g * 64];
            outv[i]      = v0;
            outv[16 + i] = v1v;
            outv[32 + i] = v2;
            if (lane == 0) outv[48] = cb;
        }
    }
}

// ---------------- Pass 2: weights -> sigmoid gate -> output ----------------
// One wave per (group, 256-column chunk), REVERSE traversal (freshest L3 lines
// first after sumprep's forward stream), NT stores (out doesn't allocate in L3,
// so x's resident lines survive the write stream).
__global__ __launch_bounds__(256) void apply_kernel(const float* __restrict__ x,
                                                    const float* __restrict__ vw,
                                                    float* __restrict__ out) {
    int wavg = (blockIdx.x * 256 + threadIdx.x) >> 6;   // 0..16383
    int lane = threadIdx.x & 63;
    int g  = NG - 1 - (wavg >> 5);          // 511..0
    int c0 = (31 - (wavg & 31)) * 256;      // reverse chunks within group too
    const float* vp = &vw[g * 64];

    const float cb = vp[48];
    float w0 = cb, w1a = cb, w2a = cb, w3a = cb;
    float4 xv[CG];
    #pragma unroll
    for (int i = 0; i < CG; ++i) {
        size_t rb = ((size_t)(g * CG + i)) * LLEN + c0;
        float4 v = *reinterpret_cast<const float4*>(x + rb + 4 * lane);
        xv[i] = v;
        float le = 0.f, re = 0.f;
        if (c0 > 0)            le = x[rb - 1];          // uniform addr -> scalar load
        if (c0 + 256 < LLEN)   re = x[rb + 256];
        float fl = __shfl_up(v.w, 1, 64);
        if (lane == 0)  fl = le;
        float fr = __shfl_down(v.x, 1, 64);
        if (lane == 63) fr = re;
        const float a0 = vp[i], a1 = vp[16 + i], a2 = vp[32 + i];
        w0  += a0 * fl  + a1 * v.x + a2 * v.y;
        w1a += a0 * v.x + a1 * v.y + a2 * v.z;
        w2a += a0 * v.y + a1 * v.z + a2 * v.w;
        w3a += a0 * v.z + a1 * v.w + a2 * fr;
    }
    const float s0 = 1.f / (1.f + __expf(-w0));
    const float s1 = 1.f / (1.f + __expf(-w1a));
    const float s2 = 1.f / (1.f + __expf(-w2a));
    const float s3 = 1.f / (1.f + __expf(-w3a));
    #pragma unroll
    for (int i = 0; i < CG; ++i) {
        size_t rb = ((size_t)(g * CG + i)) * LLEN + c0 + 4 * lane;
        float4 v = xv[i];
        f32x4 o4 = { v.x * s0, v.y * s1, v.z * s2, v.w * s3 };
        __builtin_nontemporal_store(o4, reinterpret_cast<f32x4*>(out + rb));
    }
}

extern "C" void kernel_launch(void* const* d_in, const int* in_sizes, int n_in,
                              void* d_out, int out_size, void* d_ws, size_t ws_size,
                              hipStream_t stream) {
    const float* x  = (const float*)d_in[0];
    const float* w1 = (const float*)d_in[1];
    const float* b1 = (const float*)d_in[2];
    const float* w3 = (const float*)d_in[3];
    const float* b3 = (const float*)d_in[4];
    float* out = (float*)d_out;
    float* vw  = (float*)d_ws;              // 512 * 64 floats

    // Pass 1: one block per group, 16 waves (one per row), prep fused in-block.
    sumprep_kernel<<<NG, 1024, 0, stream>>>(x, w1, b1, w3, b3, vw);
    // Pass 2: 512 groups * 32 chunks = 16384 waves / 4 per block, reverse order, NT.
    apply_kernel<<<4096, 256, 0, stream>>>(x, vw, out);
}